// Round 1
// baseline (654.975 us; speedup 1.0000x reference)
//
#include <hip/hip_runtime.h>
#include <hip/hip_bf16.h>
#include <stdint.h>

#define BB 8
#define CC 640
#define HH 64
#define WWID 64
#define HWSZ 4096
#define RR 4
#define KD 160
#define VH 16
#define VW 16
#define KTOT 1280
#define TEMP 0.1f

#define BM 128
#define BN 128
#define BK 64

typedef __bf16 bf16x8 __attribute__((ext_vector_type(8)));
typedef short  short8 __attribute__((ext_vector_type(8)));
typedef float  f32x4  __attribute__((ext_vector_type(4)));

__device__ __forceinline__ unsigned short f2bf(float f) {
    union { float f; uint32_t u; } v; v.f = f;
    uint32_t u = v.u;
    uint32_t r = u + 0x7FFFu + ((u >> 16) & 1u);
    return (unsigned short)(r >> 16);
}
__device__ __forceinline__ float bf2f(unsigned short s) {
    union { uint32_t u; float f; } v; v.u = ((uint32_t)s) << 16;
    return v.f;
}

// ---------------- K1: per-(b,c) spatial mean ----------------
__global__ void k_mean(const float* __restrict__ cc, float* __restrict__ xm) {
    int plane = blockIdx.x;                    // b*CC + c
    const float4* p4 = (const float4*)(cc + (size_t)plane * HWSZ);
    int t = threadIdx.x;
    float s = 0.f;
    #pragma unroll
    for (int i = 0; i < 4; i++) {
        float4 v = p4[t + i * 256];
        s += v.x + v.y + v.z + v.w;
    }
    #pragma unroll
    for (int off = 32; off; off >>= 1) s += __shfl_down(s, off);
    __shared__ float red[4];
    if ((t & 63) == 0) red[t >> 6] = s;
    __syncthreads();
    if (t == 0) xm[plane] = (red[0] + red[1] + red[2] + red[3]) * (1.f / HWSZ);
}

// ---------------- K2: Wg -> bf16 cast (same layout) ----------------
__global__ void k_wbf(const float* __restrict__ Wg, unsigned short* __restrict__ Wbf) {
    int i = (blockIdx.x * 256 + threadIdx.x) * 8;
    short8 o;
    #pragma unroll
    for (int j = 0; j < 8; j++) o[j] = (short)f2bf(Wg[i + j]);
    *(short8*)&Wbf[i] = o;
}

// ---------------- K3: query / norm / sims / top2 / softmax ----------------
__global__ void k_attn(const float* __restrict__ xm, const float* __restrict__ Wq,
                       const float* __restrict__ bq, const float* __restrict__ mk,
                       float* __restrict__ attnw, int* __restrict__ topidx) {
    __shared__ float q[BB * KD];
    __shared__ float qn2[BB];
    __shared__ float kn2[RR];
    int t = threadIdx.x, lane = t & 63, wid = t >> 6;
    for (int o = wid; o < BB * KD; o += 4) {
        int b = o / KD, j = o % KD;
        const float* xr = xm + b * CC;
        const float* wr = Wq + (size_t)j * CC;
        float p = 0.f;
        for (int kk = lane; kk < CC; kk += 64) p += xr[kk] * wr[kk];
        #pragma unroll
        for (int off = 32; off; off >>= 1) p += __shfl_down(p, off);
        if (lane == 0) q[o] = p + bq[j];
    }
    __syncthreads();
    if (t < BB) {
        float s = 0.f;
        for (int j = 0; j < KD; j++) { float v = q[t * KD + j]; s += v * v; }
        qn2[t] = fmaxf(sqrtf(s), 1e-12f);
    }
    if (t >= 64 && t < 64 + RR) {
        int r = t - 64; float s = 0.f;
        for (int j = 0; j < KD; j++) { float v = mk[r * KD + j]; s += v * v; }
        kn2[r] = fmaxf(sqrtf(s), 1e-12f);
    }
    __syncthreads();
    if (t < BB) {
        float sims[RR];
        for (int r = 0; r < RR; r++) {
            float s = 0.f;
            for (int j = 0; j < KD; j++) s += q[t * KD + j] * mk[r * KD + j];
            sims[r] = s / (qn2[t] * kn2[r]);
        }
        int i1 = 0;
        for (int r = 1; r < RR; r++) if (sims[r] > sims[i1]) i1 = r;
        int i2 = -1;
        for (int r = 0; r < RR; r++) { if (r == i1) continue; if (i2 < 0 || sims[r] > sims[i2]) i2 = r; }
        float e2 = expf((sims[i2] - sims[i1]) / TEMP);
        float a1 = 1.f / (1.f + e2);
        attnw[t * 2 + 0] = a1;
        attnw[t * 2 + 1] = e2 * a1;
        topidx[t * 2 + 0] = i1;
        topidx[t * 2 + 1] = i2;
    }
}

// ---------------- K4: weighted_ref = attn-combined bilinear upsample -> bf16 ----------------
__global__ void k_wref(const float* __restrict__ vc, const float* __restrict__ attnw,
                       const int* __restrict__ topidx, unsigned short* __restrict__ wrb) {
    int blk = blockIdx.x;                      // b*CC + c
    int b = blk / CC, c = blk % CC;
    __shared__ float plane[VH * VW];
    int t = threadIdx.x;
    int i1 = topidx[b * 2], i2 = topidx[b * 2 + 1];
    float a1 = attnw[b * 2], a2 = attnw[b * 2 + 1];
    const float* p1 = vc + ((size_t)(i1 * BB + b) * CC + c) * (VH * VW);
    const float* p2 = vc + ((size_t)(i2 * BB + b) * CC + c) * (VH * VW);
    plane[t] = a1 * p1[t] + a2 * p2[t];
    __syncthreads();
    unsigned short* out = wrb + ((size_t)b * CC + c) * HWSZ;
    #pragma unroll
    for (int i = 0; i < 16; i++) {
        int idx = t + i * 256;
        int y = idx >> 6, x = idx & 63;
        float py = y * 0.25f - 0.375f;
        int iy = (int)floorf(py);
        float fy = py - (float)iy;
        int y0 = max(iy, 0), y1 = min(iy + 1, VH - 1);
        float px = x * 0.25f - 0.375f;
        int ix = (int)floorf(px);
        float fx = px - (float)ix;
        int x0 = max(ix, 0), x1 = min(ix + 1, VW - 1);
        float v00 = plane[y0 * VW + x0], v01 = plane[y0 * VW + x1];
        float v10 = plane[y1 * VW + x0], v11 = plane[y1 * VW + x1];
        float v = (1.f - fy) * ((1.f - fx) * v00 + fx * v01)
                +        fy  * ((1.f - fx) * v10 + fx * v11);
        out[idx] = f2bf(v);
    }
}

// ---------------- K5: GEMM (Wg_bf16 x [cc;wr]_bf16) + sigmoid-gate epilogue ----------------
__global__ __launch_bounds__(256) void k_gemm(
    const unsigned short* __restrict__ Wbf,   // [CC][KTOT]
    const float* __restrict__ cc,             // [BB][CC][HWSZ]
    const unsigned short* __restrict__ wrb,   // [BB][CC][HWSZ]
    const float* __restrict__ bg,             // [CC]
    float* __restrict__ out)                  // [BB][CC][HWSZ]
{
    __shared__ unsigned short Wt[BM * BK];    // [row][k], 16B chunks XOR-swizzled by (row&7)
    __shared__ unsigned short Xt[BN * BK];    // [pix][k], same swizzle

    const int t = threadIdx.x;
    const int lane = t & 63;
    const int w = t >> 6;
    const int mt = blockIdx.x, nt = blockIdx.y, b = blockIdx.z;
    const int mbase = mt * BM;
    const int hwbase = nt * BN;

    f32x4 acc[4][4];
    #pragma unroll
    for (int i = 0; i < 4; i++)
        #pragma unroll
        for (int j = 0; j < 4; j++) acc[i][j] = (f32x4){0.f, 0.f, 0.f, 0.f};

    const int wm = (w >> 1) * 64;     // channel sub-tile
    const int wn = (w & 1) * 64;      // pixel sub-tile
    const int lrow = lane & 15;
    const int lkoff = (lane >> 4) * 8;

    for (int ks = 0; ks < KTOT / BK; ks++) {
        const int kb = ks * BK;
        if (ks) __syncthreads();

        // --- stage W tile: global_load_lds, source pre-swizzled so logical LDS layout is XOR-swizzled
        #pragma unroll
        for (int i = 0; i < 4; i++) {
            int c = i * 256 + t;
            int row = c >> 3, pos = c & 7;
            int oct = pos ^ (row & 7);
            const unsigned short* g = Wbf + (size_t)(mbase + row) * KTOT + kb + oct * 8;
            unsigned short* l = Wt + ((size_t)(i * 256 + (t & ~63))) * 8;
            __builtin_amdgcn_global_load_lds((const __attribute__((address_space(1))) void*)g,
                                             (__attribute__((address_space(3))) void*)l, 16, 0, 0);
        }

        // --- stage X tile: transpose [k][pix] -> LDS [pix][k] with bf16 convert
        if (kb < CC) {
            const float* src = cc + ((size_t)b * CC + kb) * HWSZ + hwbase;
            #pragma unroll
            for (int i = 0; i < 4; i++) {
                int c = i * 256 + t;
                int pix = c & 127, oct = c >> 7;
                const float* s = src + (size_t)oct * 8 * HWSZ + pix;
                short8 pv;
                #pragma unroll
                for (int j = 0; j < 8; j++) pv[j] = (short)f2bf(s[(size_t)j * HWSZ]);
                int idx = pix * BK + ((oct * 8) ^ ((pix & 7) << 3));
                *(short8*)&Xt[idx] = pv;
            }
        } else {
            const unsigned short* src = wrb + ((size_t)b * CC + (kb - CC)) * HWSZ + hwbase;
            #pragma unroll
            for (int i = 0; i < 4; i++) {
                int c = i * 256 + t;
                int pix = c & 127, oct = c >> 7;
                const unsigned short* s = src + (size_t)oct * 8 * HWSZ + pix;
                short8 pv;
                #pragma unroll
                for (int j = 0; j < 8; j++) pv[j] = (short)s[(size_t)j * HWSZ];
                int idx = pix * BK + ((oct * 8) ^ ((pix & 7) << 3));
                *(short8*)&Xt[idx] = pv;
            }
        }
        __syncthreads();

        // --- compute: 2 k-halves x 4x4 MFMA tiles per wave
        #pragma unroll
        for (int ki = 0; ki < 2; ki++) {
            bf16x8 af[4], bfr[4];
            const int kk = ki * 32 + lkoff;
            #pragma unroll
            for (int mi = 0; mi < 4; mi++) {
                int row = wm + mi * 16 + lrow;
                af[mi] = *(const bf16x8*)&Wt[row * BK + (kk ^ ((row & 7) << 3))];
            }
            #pragma unroll
            for (int ni = 0; ni < 4; ni++) {
                int prow = wn + ni * 16 + lrow;
                bfr[ni] = *(const bf16x8*)&Xt[prow * BK + (kk ^ ((prow & 7) << 3))];
            }
            #pragma unroll
            for (int mi = 0; mi < 4; mi++)
                #pragma unroll
                for (int ni = 0; ni < 4; ni++)
                    acc[mi][ni] = __builtin_amdgcn_mfma_f32_16x16x32_bf16(af[mi], bfr[ni], acc[mi][ni], 0, 0, 0);
        }
    }

    // --- epilogue: gate = sigmoid(acc + bg); out = g*wr + (1-g)*cc
    const size_t pb = (size_t)b * CC * HWSZ;
    #pragma unroll
    for (int mi = 0; mi < 4; mi++) {
        #pragma unroll
        for (int r = 0; r < 4; r++) {
            int ch = mbase + wm + mi * 16 + (lane >> 4) * 4 + r;
            float bgv = bg[ch];
            size_t rowoff = pb + (size_t)ch * HWSZ;
            #pragma unroll
            for (int ni = 0; ni < 4; ni++) {
                int pix = hwbase + wn + ni * 16 + (lane & 15);
                float gp = acc[mi][ni][r] + bgv;
                float g = 1.f / (1.f + expf(-gp));
                float wv = bf2f(wrb[rowoff + pix]);
                float cv = cc[rowoff + pix];
                out[rowoff + pix] = g * wv + (1.f - g) * cv;
            }
        }
    }
}

extern "C" void kernel_launch(void* const* d_in, const int* in_sizes, int n_in,
                              void* d_out, int out_size, void* d_ws, size_t ws_size,
                              hipStream_t stream) {
    const float* cc = (const float*)d_in[0];
    const float* Wq = (const float*)d_in[1];
    const float* bq = (const float*)d_in[2];
    const float* mk = (const float*)d_in[3];
    const float* vc = (const float*)d_in[4];
    const float* Wg = (const float*)d_in[5];
    const float* bg = (const float*)d_in[6];
    float* out = (float*)d_out;

    char* ws = (char*)d_ws;
    float* xm            = (float*)ws;                          // 5120 f = 20480 B
    float* attnw         = (float*)(ws + 20480);                // 16 f
    int*   topidx        = (int*)(ws + 20544);                  // 16 i
    unsigned short* Wbf  = (unsigned short*)(ws + 20736);       // 640*1280*2 = 1638400 B
    unsigned short* wrb  = (unsigned short*)(ws + 20736 + 1638400); // 8*640*4096*2 = 41.9 MB

    k_mean<<<BB * CC, 256, 0, stream>>>(cc, xm);
    k_wbf<<<(CC * KTOT) / (256 * 8), 256, 0, stream>>>(Wg, Wbf);
    k_attn<<<1, 256, 0, stream>>>(xm, Wq, bq, mk, attnw, topidx);
    k_wref<<<BB * CC, 256, 0, stream>>>(vc, attnw, topidx, wrb);
    dim3 g(CC / BM, HWSZ / BN, BB);
    k_gemm<<<g, 256, 0, stream>>>(Wbf, cc, wrb, bg, out);
}

// Round 2
// 171.734 us; speedup vs baseline: 3.8139x; 3.8139x over previous
//
#include <hip/hip_runtime.h>
#include <hip/hip_bf16.h>
#include <stdint.h>

#define BB 8
#define CC 640
#define HH 64
#define WWID 64
#define HWSZ 4096
#define RR 4
#define KD 160
#define VH 16
#define VW 16
#define KTOT 1280
#define TEMP 0.1f

#define BM 128
#define BN 128
#define BK 64

typedef __bf16 bf16x8 __attribute__((ext_vector_type(8)));
typedef short  short8 __attribute__((ext_vector_type(8)));
typedef float  f32x4  __attribute__((ext_vector_type(4)));

__device__ __forceinline__ unsigned short f2bf(float f) {
    union { float f; uint32_t u; } v; v.f = f;
    uint32_t u = v.u;
    uint32_t r = u + 0x7FFFu + ((u >> 16) & 1u);
    return (unsigned short)(r >> 16);
}
__device__ __forceinline__ float bf2f(unsigned short s) {
    union { uint32_t u; float f; } v; v.u = ((uint32_t)s) << 16;
    return v.f;
}

// ---------------- K1: per-(b,c) spatial mean ----------------
__global__ void k_mean(const float* __restrict__ cc, float* __restrict__ xm) {
    int plane = blockIdx.x;                    // b*CC + c
    const float4* p4 = (const float4*)(cc + (size_t)plane * HWSZ);
    int t = threadIdx.x;
    float s = 0.f;
    #pragma unroll
    for (int i = 0; i < 4; i++) {
        float4 v = p4[t + i * 256];
        s += v.x + v.y + v.z + v.w;
    }
    #pragma unroll
    for (int off = 32; off; off >>= 1) s += __shfl_down(s, off);
    __shared__ float red[4];
    if ((t & 63) == 0) red[t >> 6] = s;
    __syncthreads();
    if (t == 0) xm[plane] = (red[0] + red[1] + red[2] + red[3]) * (1.f / HWSZ);
}

// ---------------- K2: Wg -> bf16 cast (same layout) ----------------
__global__ void k_wbf(const float* __restrict__ Wg, unsigned short* __restrict__ Wbf) {
    int i = (blockIdx.x * 256 + threadIdx.x) * 8;
    short8 o;
    #pragma unroll
    for (int j = 0; j < 8; j++) o[j] = (short)f2bf(Wg[i + j]);
    *(short8*)&Wbf[i] = o;
}

// ---------------- K3a: query = xm @ Wq.T + bq  (one wave per output) ----------------
__global__ void k_query(const float* __restrict__ xm, const float* __restrict__ Wq,
                        const float* __restrict__ bq, float* __restrict__ q) {
    int o = blockIdx.x;                        // b*KD + j
    int b = o / KD, j = o % KD;
    int lane = threadIdx.x;
    const float* xr = xm + b * CC;
    const float* wr = Wq + (size_t)j * CC;
    float p = 0.f;
    #pragma unroll
    for (int i = 0; i < CC / 64; i++) {
        int kk = lane + i * 64;
        p += xr[kk] * wr[kk];
    }
    #pragma unroll
    for (int off = 32; off; off >>= 1) p += __shfl_down(p, off);
    if (lane == 0) q[o] = p + bq[j];
}

// ---------------- K3b: norms / sims / top2 / softmax (wave per batch) ----------------
__global__ void k_attn2(const float* __restrict__ q, const float* __restrict__ mk,
                        float* __restrict__ attnw, int* __restrict__ topidx) {
    int t = threadIdx.x, lane = t & 63, b = t >> 6;   // 8 waves, one per batch
    __shared__ float smk[RR * KD];
    for (int i = t; i < RR * KD; i += 512) smk[i] = mk[i];
    __syncthreads();
    const float* qr = q + b * KD;
    float qv[3];
    float s = 0.f;
    #pragma unroll
    for (int i = 0; i < 3; i++) {
        int idx = lane + i * 64;
        qv[i] = (idx < KD) ? qr[idx] : 0.f;
        s += qv[i] * qv[i];
    }
    #pragma unroll
    for (int off = 32; off; off >>= 1) s += __shfl_xor(s, off);
    float qn = fmaxf(sqrtf(s), 1e-12f);
    float sims[RR];
    #pragma unroll
    for (int r = 0; r < RR; r++) {
        float d = 0.f, kn2 = 0.f;
        #pragma unroll
        for (int i = 0; i < 3; i++) {
            int idx = lane + i * 64;
            float m = (idx < KD) ? smk[r * KD + idx] : 0.f;
            d += qv[i] * m;
            kn2 += m * m;
        }
        #pragma unroll
        for (int off = 32; off; off >>= 1) {
            d += __shfl_xor(d, off);
            kn2 += __shfl_xor(kn2, off);
        }
        sims[r] = d / (qn * fmaxf(sqrtf(kn2), 1e-12f));
    }
    if (lane == 0) {
        int i1 = 0;
        for (int r = 1; r < RR; r++) if (sims[r] > sims[i1]) i1 = r;
        int i2 = -1;
        for (int r = 0; r < RR; r++) { if (r == i1) continue; if (i2 < 0 || sims[r] > sims[i2]) i2 = r; }
        float e2 = expf((sims[i2] - sims[i1]) / TEMP);
        float a1 = 1.f / (1.f + e2);
        attnw[b * 2 + 0] = a1;
        attnw[b * 2 + 1] = e2 * a1;
        topidx[b * 2 + 0] = i1;
        topidx[b * 2 + 1] = i2;
    }
}

// ---------------- K4: weighted_ref = attn-combined bilinear upsample -> bf16 ----------------
__global__ void k_wref(const float* __restrict__ vc, const float* __restrict__ attnw,
                       const int* __restrict__ topidx, unsigned short* __restrict__ wrb) {
    int blk = blockIdx.x;                      // b*CC + c
    int b = blk / CC, c = blk % CC;
    __shared__ float plane[VH * VW];
    int t = threadIdx.x;
    int i1 = topidx[b * 2], i2 = topidx[b * 2 + 1];
    float a1 = attnw[b * 2], a2 = attnw[b * 2 + 1];
    const float* p1 = vc + ((size_t)(i1 * BB + b) * CC + c) * (VH * VW);
    const float* p2 = vc + ((size_t)(i2 * BB + b) * CC + c) * (VH * VW);
    plane[t] = a1 * p1[t] + a2 * p2[t];
    __syncthreads();
    unsigned short* out = wrb + ((size_t)b * CC + c) * HWSZ;
    #pragma unroll
    for (int i = 0; i < 16; i++) {
        int idx = t + i * 256;
        int y = idx >> 6, x = idx & 63;
        float py = y * 0.25f - 0.375f;
        int iy = (int)floorf(py);
        float fy = py - (float)iy;
        int y0 = max(iy, 0), y1 = min(iy + 1, VH - 1);
        float px = x * 0.25f - 0.375f;
        int ix = (int)floorf(px);
        float fx = px - (float)ix;
        int x0 = max(ix, 0), x1 = min(ix + 1, VW - 1);
        float v00 = plane[y0 * VW + x0], v01 = plane[y0 * VW + x1];
        float v10 = plane[y1 * VW + x0], v11 = plane[y1 * VW + x1];
        float v = (1.f - fy) * ((1.f - fx) * v00 + fx * v01)
                +        fy  * ((1.f - fx) * v10 + fx * v11);
        out[idx] = f2bf(v);
    }
}

// ---------------- K5: GEMM (Wg_bf16 x [cc;wr]_bf16) + sigmoid-gate epilogue ----------------
__global__ __launch_bounds__(256) void k_gemm(
    const unsigned short* __restrict__ Wbf,   // [CC][KTOT]
    const float* __restrict__ cc,             // [BB][CC][HWSZ]
    const unsigned short* __restrict__ wrb,   // [BB][CC][HWSZ]
    const float* __restrict__ bg,             // [CC]
    float* __restrict__ out)                  // [BB][CC][HWSZ]
{
    __shared__ unsigned short Wt[BM * BK];    // [row][k], 16B chunks XOR-swizzled by (row&7)
    __shared__ unsigned short Xt[BN * BK];    // [pix][k], same swizzle

    const int t = threadIdx.x;
    const int lane = t & 63;
    const int w = t >> 6;
    const int mt = blockIdx.x, nt = blockIdx.y, b = blockIdx.z;
    const int mbase = mt * BM;
    const int hwbase = nt * BN;

    f32x4 acc[4][4];
    #pragma unroll
    for (int i = 0; i < 4; i++)
        #pragma unroll
        for (int j = 0; j < 4; j++) acc[i][j] = (f32x4){0.f, 0.f, 0.f, 0.f};

    const int wm = (w >> 1) * 64;     // channel sub-tile
    const int wn = (w & 1) * 64;      // pixel sub-tile
    const int lrow = lane & 15;
    const int lkoff = (lane >> 4) * 8;

    for (int ks = 0; ks < KTOT / BK; ks++) {
        const int kb = ks * BK;
        if (ks) __syncthreads();

        // --- stage W tile: global_load_lds, source pre-swizzled so logical LDS layout is XOR-swizzled
        #pragma unroll
        for (int i = 0; i < 4; i++) {
            int c = i * 256 + t;
            int row = c >> 3, pos = c & 7;
            int oct = pos ^ (row & 7);
            const unsigned short* g = Wbf + (size_t)(mbase + row) * KTOT + kb + oct * 8;
            unsigned short* l = Wt + ((size_t)(i * 256 + (t & ~63))) * 8;
            __builtin_amdgcn_global_load_lds((const __attribute__((address_space(1))) void*)g,
                                             (__attribute__((address_space(3))) void*)l, 16, 0, 0);
        }

        // --- stage X tile: transpose [k][pix] -> LDS [pix][k] with bf16 convert
        if (kb < CC) {
            const float* src = cc + ((size_t)b * CC + kb) * HWSZ + hwbase;
            #pragma unroll
            for (int i = 0; i < 4; i++) {
                int c = i * 256 + t;
                int pix = c & 127, oct = c >> 7;
                const float* s = src + (size_t)oct * 8 * HWSZ + pix;
                short8 pv;
                #pragma unroll
                for (int j = 0; j < 8; j++) pv[j] = (short)f2bf(s[(size_t)j * HWSZ]);
                int idx = pix * BK + ((oct * 8) ^ ((pix & 7) << 3));
                *(short8*)&Xt[idx] = pv;
            }
        } else {
            const unsigned short* src = wrb + ((size_t)b * CC + (kb - CC)) * HWSZ + hwbase;
            #pragma unroll
            for (int i = 0; i < 4; i++) {
                int c = i * 256 + t;
                int pix = c & 127, oct = c >> 7;
                const unsigned short* s = src + (size_t)oct * 8 * HWSZ + pix;
                short8 pv;
                #pragma unroll
                for (int j = 0; j < 8; j++) pv[j] = (short)s[(size_t)j * HWSZ];
                int idx = pix * BK + ((oct * 8) ^ ((pix & 7) << 3));
                *(short8*)&Xt[idx] = pv;
            }
        }
        __syncthreads();

        // --- compute: 2 k-halves x 4x4 MFMA tiles per wave
        #pragma unroll
        for (int ki = 0; ki < 2; ki++) {
            bf16x8 af[4], bfr[4];
            const int kk = ki * 32 + lkoff;
            #pragma unroll
            for (int mi = 0; mi < 4; mi++) {
                int row = wm + mi * 16 + lrow;
                af[mi] = *(const bf16x8*)&Wt[row * BK + (kk ^ ((row & 7) << 3))];
            }
            #pragma unroll
            for (int ni = 0; ni < 4; ni++) {
                int prow = wn + ni * 16 + lrow;
                bfr[ni] = *(const bf16x8*)&Xt[prow * BK + (kk ^ ((prow & 7) << 3))];
            }
            #pragma unroll
            for (int mi = 0; mi < 4; mi++)
                #pragma unroll
                for (int ni = 0; ni < 4; ni++)
                    acc[mi][ni] = __builtin_amdgcn_mfma_f32_16x16x32_bf16(af[mi], bfr[ni], acc[mi][ni], 0, 0, 0);
        }
    }

    // --- epilogue: gate = sigmoid(acc + bg); out = g*wr + (1-g)*cc
    const size_t pb = (size_t)b * CC * HWSZ;
    #pragma unroll
    for (int mi = 0; mi < 4; mi++) {
        #pragma unroll
        for (int r = 0; r < 4; r++) {
            int ch = mbase + wm + mi * 16 + (lane >> 4) * 4 + r;
            float bgv = bg[ch];
            size_t rowoff = pb + (size_t)ch * HWSZ;
            #pragma unroll
            for (int ni = 0; ni < 4; ni++) {
                int pix = hwbase + wn + ni * 16 + (lane & 15);
                float gp = acc[mi][ni][r] + bgv;
                float g = 1.f / (1.f + expf(-gp));
                float wv = bf2f(wrb[rowoff + pix]);
                float cv = cc[rowoff + pix];
                out[rowoff + pix] = g * wv + (1.f - g) * cv;
            }
        }
    }
}

extern "C" void kernel_launch(void* const* d_in, const int* in_sizes, int n_in,
                              void* d_out, int out_size, void* d_ws, size_t ws_size,
                              hipStream_t stream) {
    const float* cc = (const float*)d_in[0];
    const float* Wq = (const float*)d_in[1];
    const float* bq = (const float*)d_in[2];
    const float* mk = (const float*)d_in[3];
    const float* vc = (const float*)d_in[4];
    const float* Wg = (const float*)d_in[5];
    const float* bg = (const float*)d_in[6];
    float* out = (float*)d_out;

    char* ws = (char*)d_ws;
    float* xm            = (float*)ws;                          // 5120 f = 20480 B
    float* attnw         = (float*)(ws + 20480);                // 16 f
    int*   topidx        = (int*)(ws + 20544);                  // 16 i
    float* q             = (float*)(ws + 20608);                // 1280 f = 5120 B
    unsigned short* Wbf  = (unsigned short*)(ws + 25728);       // 640*1280*2 = 1638400 B
    unsigned short* wrb  = (unsigned short*)(ws + 25728 + 1638400); // 8*640*4096*2 = 41.9 MB

    k_mean<<<BB * CC, 256, 0, stream>>>(cc, xm);
    k_wbf<<<(CC * KTOT) / (256 * 8), 256, 0, stream>>>(Wg, Wbf);
    k_query<<<BB * KD, 64, 0, stream>>>(xm, Wq, bq, q);
    k_attn2<<<1, 512, 0, stream>>>(q, mk, attnw, topidx);
    k_wref<<<BB * CC, 256, 0, stream>>>(vc, attnw, topidx, wrb);
    dim3 g(CC / BM, HWSZ / BN, BB);
    k_gemm<<<g, 256, 0, stream>>>(Wbf, cc, wrb, bg, out);
}

// Round 3
// 167.434 us; speedup vs baseline: 3.9118x; 1.0257x over previous
//
#include <hip/hip_runtime.h>
#include <hip/hip_bf16.h>
#include <stdint.h>

#define BB 8
#define CC 640
#define HH 64
#define WWID 64
#define HWSZ 4096
#define RR 4
#define KD 160
#define VH 16
#define VW 16
#define KTOT 1280
#define TEMP 0.1f

#define BM 128
#define BN 128
#define BK 64

typedef __bf16 bf16x8 __attribute__((ext_vector_type(8)));
typedef short  short8 __attribute__((ext_vector_type(8)));
typedef float  f32x4  __attribute__((ext_vector_type(4)));

__device__ __forceinline__ unsigned short f2bf(float f) {
    union { float f; uint32_t u; } v; v.f = f;
    uint32_t u = v.u;
    uint32_t r = u + 0x7FFFu + ((u >> 16) & 1u);
    return (unsigned short)(r >> 16);
}
__device__ __forceinline__ float bf2f(unsigned short s) {
    union { uint32_t u; float f; } v; v.u = ((uint32_t)s) << 16;
    return v.f;
}

// ---------------- K1: per-(b,c) spatial mean ----------------
__global__ void k_mean(const float* __restrict__ cc, float* __restrict__ xm) {
    int plane = blockIdx.x;                    // b*CC + c
    const float4* p4 = (const float4*)(cc + (size_t)plane * HWSZ);
    int t = threadIdx.x;
    float s = 0.f;
    #pragma unroll
    for (int i = 0; i < 4; i++) {
        float4 v = p4[t + i * 256];
        s += v.x + v.y + v.z + v.w;
    }
    #pragma unroll
    for (int off = 32; off; off >>= 1) s += __shfl_down(s, off);
    __shared__ float red[4];
    if ((t & 63) == 0) red[t >> 6] = s;
    __syncthreads();
    if (t == 0) xm[plane] = (red[0] + red[1] + red[2] + red[3]) * (1.f / HWSZ);
}

// ---------------- K2: Wg -> bf16 cast (same layout) ----------------
__global__ void k_wbf(const float* __restrict__ Wg, unsigned short* __restrict__ Wbf) {
    int i = (blockIdx.x * 256 + threadIdx.x) * 8;
    short8 o;
    #pragma unroll
    for (int j = 0; j < 8; j++) o[j] = (short)f2bf(Wg[i + j]);
    *(short8*)&Wbf[i] = o;
}

// ---------------- K3a: query = xm @ Wq.T + bq  (one wave per output) ----------------
__global__ void k_query(const float* __restrict__ xm, const float* __restrict__ Wq,
                        const float* __restrict__ bq, float* __restrict__ q) {
    int o = blockIdx.x;                        // b*KD + j
    int b = o / KD, j = o % KD;
    int lane = threadIdx.x;
    const float* xr = xm + b * CC;
    const float* wr = Wq + (size_t)j * CC;
    float p = 0.f;
    #pragma unroll
    for (int i = 0; i < CC / 64; i++) {
        int kk = lane + i * 64;
        p += xr[kk] * wr[kk];
    }
    #pragma unroll
    for (int off = 32; off; off >>= 1) p += __shfl_down(p, off);
    if (lane == 0) q[o] = p + bq[j];
}

// ---------------- K3b: norms / sims / top2 / softmax (wave per batch) ----------------
__global__ void k_attn2(const float* __restrict__ q, const float* __restrict__ mk,
                        float* __restrict__ attnw, int* __restrict__ topidx) {
    int t = threadIdx.x, lane = t & 63, b = t >> 6;   // 8 waves, one per batch
    __shared__ float smk[RR * KD];
    for (int i = t; i < RR * KD; i += 512) smk[i] = mk[i];
    __syncthreads();
    const float* qr = q + b * KD;
    float qv[3];
    float s = 0.f;
    #pragma unroll
    for (int i = 0; i < 3; i++) {
        int idx = lane + i * 64;
        qv[i] = (idx < KD) ? qr[idx] : 0.f;
        s += qv[i] * qv[i];
    }
    #pragma unroll
    for (int off = 32; off; off >>= 1) s += __shfl_xor(s, off);
    float qn = fmaxf(sqrtf(s), 1e-12f);
    float sims[RR];
    #pragma unroll
    for (int r = 0; r < RR; r++) {
        float d = 0.f, kn2 = 0.f;
        #pragma unroll
        for (int i = 0; i < 3; i++) {
            int idx = lane + i * 64;
            float m = (idx < KD) ? smk[r * KD + idx] : 0.f;
            d += qv[i] * m;
            kn2 += m * m;
        }
        #pragma unroll
        for (int off = 32; off; off >>= 1) {
            d += __shfl_xor(d, off);
            kn2 += __shfl_xor(kn2, off);
        }
        sims[r] = d / (qn * fmaxf(sqrtf(kn2), 1e-12f));
    }
    if (lane == 0) {
        int i1 = 0;
        for (int r = 1; r < RR; r++) if (sims[r] > sims[i1]) i1 = r;
        int i2 = -1;
        for (int r = 0; r < RR; r++) { if (r == i1) continue; if (i2 < 0 || sims[r] > sims[i2]) i2 = r; }
        float e2 = expf((sims[i2] - sims[i1]) / TEMP);
        float a1 = 1.f / (1.f + e2);
        attnw[b * 2 + 0] = a1;
        attnw[b * 2 + 1] = e2 * a1;
        topidx[b * 2 + 0] = i1;
        topidx[b * 2 + 1] = i2;
    }
}

// ---------------- K4: weighted_ref = attn-combined bilinear upsample -> bf16 ----------------
__global__ void k_wref(const float* __restrict__ vc, const float* __restrict__ attnw,
                       const int* __restrict__ topidx, unsigned short* __restrict__ wrb) {
    int blk = blockIdx.x;                      // b*CC + c
    int b = blk / CC, c = blk % CC;
    __shared__ float plane[VH * VW];
    int t = threadIdx.x;
    int i1 = topidx[b * 2], i2 = topidx[b * 2 + 1];
    float a1 = attnw[b * 2], a2 = attnw[b * 2 + 1];
    const float* p1 = vc + ((size_t)(i1 * BB + b) * CC + c) * (VH * VW);
    const float* p2 = vc + ((size_t)(i2 * BB + b) * CC + c) * (VH * VW);
    plane[t] = a1 * p1[t] + a2 * p2[t];
    __syncthreads();
    unsigned short* out = wrb + ((size_t)b * CC + c) * HWSZ;
    #pragma unroll
    for (int i = 0; i < 16; i++) {
        int idx = t + i * 256;
        int y = idx >> 6, x = idx & 63;
        float py = y * 0.25f - 0.375f;
        int iy = (int)floorf(py);
        float fy = py - (float)iy;
        int y0 = max(iy, 0), y1 = min(iy + 1, VH - 1);
        float px = x * 0.25f - 0.375f;
        int ix = (int)floorf(px);
        float fx = px - (float)ix;
        int x0 = max(ix, 0), x1 = min(ix + 1, VW - 1);
        float v00 = plane[y0 * VW + x0], v01 = plane[y0 * VW + x1];
        float v10 = plane[y1 * VW + x0], v11 = plane[y1 * VW + x1];
        float v = (1.f - fy) * ((1.f - fx) * v00 + fx * v01)
                +        fy  * ((1.f - fx) * v10 + fx * v11);
        out[idx] = f2bf(v);
    }
}

// ---------------- K4b: build Xbf[b][pix][1280] = bf16([cc; wr]) transposed ----------------
__global__ void k_xpose(const float* __restrict__ cc, const unsigned short* __restrict__ wrb,
                        unsigned short* __restrict__ Xbf) {
    int g = blockIdx.x * 256 + threadIdx.x;    // one short8 per thread
    int p = g & (HWSZ - 1);
    int kc = (g >> 12) % 160;                  // 160 chunks of 8 k
    int b = (g >> 12) / 160;
    short8 o;
    if (kc < 80) {
        const float* s = cc + ((size_t)(b * CC + kc * 8)) * HWSZ + p;
        #pragma unroll
        for (int j = 0; j < 8; j++) o[j] = (short)f2bf(s[(size_t)j * HWSZ]);
    } else {
        const unsigned short* s = wrb + ((size_t)(b * CC + (kc - 80) * 8)) * HWSZ + p;
        #pragma unroll
        for (int j = 0; j < 8; j++) o[j] = (short)s[(size_t)j * HWSZ];
    }
    *(short8*)&Xbf[((size_t)b * HWSZ + p) * KTOT + kc * 8] = o;
}

// ---------------- K5: GEMM, both operands via global_load_lds (m97 structure) ----------------
__global__ __launch_bounds__(256) void k_gemm(
    const unsigned short* __restrict__ Wbf,   // [CC][KTOT]
    const unsigned short* __restrict__ Xbf,   // [BB][HWSZ][KTOT]
    const float* __restrict__ cc,             // [BB][CC][HWSZ]
    const unsigned short* __restrict__ wrb,   // [BB][CC][HWSZ]
    const float* __restrict__ bg,             // [CC]
    float* __restrict__ out)                  // [BB][CC][HWSZ]
{
    __shared__ unsigned short Wt[BM * BK];    // [row][k], 16B slots, slot pos holds src pos^(row&7)
    __shared__ unsigned short Xt[BN * BK];    // [pix][k], same

    const int t = threadIdx.x;
    const int lane = t & 63;
    const int w = t >> 6;

    // XCD-chunked bijective swizzle: 1280 blocks, 8 XCDs, 160 per XCD (= one batch each)
    const int orig = blockIdx.x;
    const int bid = (orig & 7) * 160 + (orig >> 3);
    const int mt = bid % 5;
    const int nt = (bid / 5) % 32;
    const int b = bid / 160;
    const int mbase = mt * BM;
    const int hwbase = nt * BN;

    f32x4 acc[4][4];
    #pragma unroll
    for (int i = 0; i < 4; i++)
        #pragma unroll
        for (int j = 0; j < 4; j++) acc[i][j] = (f32x4){0.f, 0.f, 0.f, 0.f};

    const int wm = (w >> 1) * 64;
    const int wn = (w & 1) * 64;
    const int lrow = lane & 15;
    const int lkoff = (lane >> 4) * 8;

    const int srow = t >> 3, spos = t & 7;
    const int soct = spos ^ (srow & 7);        // pre-swizzled source chunk

    for (int ks = 0; ks < KTOT / BK; ks++) {
        const int kb = ks * BK;
        if (ks) __syncthreads();

        const unsigned short* wsrc = Wbf + (size_t)mbase * KTOT + kb;
        const unsigned short* xsrc = Xbf + ((size_t)b * HWSZ + hwbase) * KTOT + kb;
        #pragma unroll
        for (int i = 0; i < 4; i++) {
            // c = i*256 + t ; row = c>>3 = i*32 + srow ; pos/oct invariant in i
            const unsigned short* gw = wsrc + (size_t)(i * 32 + srow) * KTOT + soct * 8;
            unsigned short* lw = Wt + ((size_t)(i * 256 + (t & ~63))) * 8;
            __builtin_amdgcn_global_load_lds((const __attribute__((address_space(1))) void*)gw,
                                             (__attribute__((address_space(3))) void*)lw, 16, 0, 0);
            const unsigned short* gx = xsrc + (size_t)(i * 32 + srow) * KTOT + soct * 8;
            unsigned short* lx = Xt + ((size_t)(i * 256 + (t & ~63))) * 8;
            __builtin_amdgcn_global_load_lds((const __attribute__((address_space(1))) void*)gx,
                                             (__attribute__((address_space(3))) void*)lx, 16, 0, 0);
        }
        __syncthreads();

        #pragma unroll
        for (int ki = 0; ki < 2; ki++) {
            bf16x8 af[4], bfr[4];
            const int kk = ki * 32 + lkoff;
            #pragma unroll
            for (int mi = 0; mi < 4; mi++) {
                int row = wm + mi * 16 + lrow;
                af[mi] = *(const bf16x8*)&Wt[row * BK + (kk ^ ((row & 7) << 3))];
            }
            #pragma unroll
            for (int ni = 0; ni < 4; ni++) {
                int prow = wn + ni * 16 + lrow;
                bfr[ni] = *(const bf16x8*)&Xt[prow * BK + (kk ^ ((prow & 7) << 3))];
            }
            #pragma unroll
            for (int mi = 0; mi < 4; mi++)
                #pragma unroll
                for (int ni = 0; ni < 4; ni++)
                    acc[mi][ni] = __builtin_amdgcn_mfma_f32_16x16x32_bf16(af[mi], bfr[ni], acc[mi][ni], 0, 0, 0);
        }
    }

    // --- epilogue: gate = sigmoid(acc + bg); out = g*wr + (1-g)*cc
    const size_t pb = (size_t)b * CC * HWSZ;
    #pragma unroll
    for (int mi = 0; mi < 4; mi++) {
        #pragma unroll
        for (int r = 0; r < 4; r++) {
            int ch = mbase + wm + mi * 16 + (lane >> 4) * 4 + r;
            float bgv = bg[ch];
            size_t rowoff = pb + (size_t)ch * HWSZ;
            #pragma unroll
            for (int ni = 0; ni < 4; ni++) {
                int pix = hwbase + wn + ni * 16 + (lane & 15);
                float gp = acc[mi][ni][r] + bgv;
                float g = 1.f / (1.f + expf(-gp));
                float wv = bf2f(wrb[rowoff + pix]);
                float cv = cc[rowoff + pix];
                out[rowoff + pix] = g * wv + (1.f - g) * cv;
            }
        }
    }
}

// ---------------- K5-fallback: round-2 GEMM (in-kernel transpose), used if ws too small ----
__global__ __launch_bounds__(256) void k_gemm_fb(
    const unsigned short* __restrict__ Wbf,
    const float* __restrict__ cc,
    const unsigned short* __restrict__ wrb,
    const float* __restrict__ bg,
    float* __restrict__ out)
{
    __shared__ unsigned short Wt[BM * BK];
    __shared__ unsigned short Xt[BN * BK];

    const int t = threadIdx.x;
    const int lane = t & 63;
    const int w = t >> 6;
    const int mt = blockIdx.x, nt = blockIdx.y, b = blockIdx.z;
    const int mbase = mt * BM;
    const int hwbase = nt * BN;

    f32x4 acc[4][4];
    #pragma unroll
    for (int i = 0; i < 4; i++)
        #pragma unroll
        for (int j = 0; j < 4; j++) acc[i][j] = (f32x4){0.f, 0.f, 0.f, 0.f};

    const int wm = (w >> 1) * 64;
    const int wn = (w & 1) * 64;
    const int lrow = lane & 15;
    const int lkoff = (lane >> 4) * 8;

    for (int ks = 0; ks < KTOT / BK; ks++) {
        const int kb = ks * BK;
        if (ks) __syncthreads();

        #pragma unroll
        for (int i = 0; i < 4; i++) {
            int c = i * 256 + t;
            int row = c >> 3, pos = c & 7;
            int oct = pos ^ (row & 7);
            const unsigned short* g = Wbf + (size_t)(mbase + row) * KTOT + kb + oct * 8;
            unsigned short* l = Wt + ((size_t)(i * 256 + (t & ~63))) * 8;
            __builtin_amdgcn_global_load_lds((const __attribute__((address_space(1))) void*)g,
                                             (__attribute__((address_space(3))) void*)l, 16, 0, 0);
        }

        if (kb < CC) {
            const float* src = cc + ((size_t)b * CC + kb) * HWSZ + hwbase;
            #pragma unroll
            for (int i = 0; i < 4; i++) {
                int c = i * 256 + t;
                int pix = c & 127, oct = c >> 7;
                const float* s = src + (size_t)oct * 8 * HWSZ + pix;
                short8 pv;
                #pragma unroll
                for (int j = 0; j < 8; j++) pv[j] = (short)f2bf(s[(size_t)j * HWSZ]);
                int idx = pix * BK + ((oct * 8) ^ ((pix & 7) << 3));
                *(short8*)&Xt[idx] = pv;
            }
        } else {
            const unsigned short* src = wrb + ((size_t)b * CC + (kb - CC)) * HWSZ + hwbase;
            #pragma unroll
            for (int i = 0; i < 4; i++) {
                int c = i * 256 + t;
                int pix = c & 127, oct = c >> 7;
                const unsigned short* s = src + (size_t)oct * 8 * HWSZ + pix;
                short8 pv;
                #pragma unroll
                for (int j = 0; j < 8; j++) pv[j] = (short)s[(size_t)j * HWSZ];
                int idx = pix * BK + ((oct * 8) ^ ((pix & 7) << 3));
                *(short8*)&Xt[idx] = pv;
            }
        }
        __syncthreads();

        #pragma unroll
        for (int ki = 0; ki < 2; ki++) {
            bf16x8 af[4], bfr[4];
            const int kk = ki * 32 + lkoff;
            #pragma unroll
            for (int mi = 0; mi < 4; mi++) {
                int row = wm + mi * 16 + lrow;
                af[mi] = *(const bf16x8*)&Wt[row * BK + (kk ^ ((row & 7) << 3))];
            }
            #pragma unroll
            for (int ni = 0; ni < 4; ni++) {
                int prow = wn + ni * 16 + lrow;
                bfr[ni] = *(const bf16x8*)&Xt[prow * BK + (kk ^ ((prow & 7) << 3))];
            }
            #pragma unroll
            for (int mi = 0; mi < 4; mi++)
                #pragma unroll
                for (int ni = 0; ni < 4; ni++)
                    acc[mi][ni] = __builtin_amdgcn_mfma_f32_16x16x32_bf16(af[mi], bfr[ni], acc[mi][ni], 0, 0, 0);
        }
    }

    const size_t pb = (size_t)b * CC * HWSZ;
    #pragma unroll
    for (int mi = 0; mi < 4; mi++) {
        #pragma unroll
        for (int r = 0; r < 4; r++) {
            int ch = mbase + wm + mi * 16 + (lane >> 4) * 4 + r;
            float bgv = bg[ch];
            size_t rowoff = pb + (size_t)ch * HWSZ;
            #pragma unroll
            for (int ni = 0; ni < 4; ni++) {
                int pix = hwbase + wn + ni * 16 + (lane & 15);
                float gp = acc[mi][ni][r] + bgv;
                float g = 1.f / (1.f + expf(-gp));
                float wv = bf2f(wrb[rowoff + pix]);
                float cv = cc[rowoff + pix];
                out[rowoff + pix] = g * wv + (1.f - g) * cv;
            }
        }
    }
}

extern "C" void kernel_launch(void* const* d_in, const int* in_sizes, int n_in,
                              void* d_out, int out_size, void* d_ws, size_t ws_size,
                              hipStream_t stream) {
    const float* cc = (const float*)d_in[0];
    const float* Wq = (const float*)d_in[1];
    const float* bq = (const float*)d_in[2];
    const float* mk = (const float*)d_in[3];
    const float* vc = (const float*)d_in[4];
    const float* Wg = (const float*)d_in[5];
    const float* bg = (const float*)d_in[6];
    float* out = (float*)d_out;

    char* ws = (char*)d_ws;
    float* xm            = (float*)ws;                               // 20480 B
    float* attnw         = (float*)(ws + 20480);                     // 64 B
    int*   topidx        = (int*)(ws + 20544);                       // 64 B
    float* q             = (float*)(ws + 20608);                     // 5120 B
    unsigned short* Wbf  = (unsigned short*)(ws + 25728);            // 1,638,400 B
    unsigned short* wrb  = (unsigned short*)(ws + 25728 + 1638400);  // 41,943,040 B
    size_t xbf_off       = 25728 + 1638400 + 41943040ULL;
    unsigned short* Xbf  = (unsigned short*)(ws + xbf_off);          // 83,886,080 B
    const size_t need    = xbf_off + 83886080ULL;

    k_mean<<<BB * CC, 256, 0, stream>>>(cc, xm);
    k_wbf<<<(CC * KTOT) / (256 * 8), 256, 0, stream>>>(Wg, Wbf);
    k_query<<<BB * KD, 64, 0, stream>>>(xm, Wq, bq, q);
    k_attn2<<<1, 512, 0, stream>>>(q, mk, attnw, topidx);
    k_wref<<<BB * CC, 256, 0, stream>>>(vc, attnw, topidx, wrb);

    if (ws_size >= need) {
        k_xpose<<<(BB * 160 * HWSZ) / 256, 256, 0, stream>>>(cc, wrb, Xbf);
        k_gemm<<<1280, 256, 0, stream>>>(Wbf, Xbf, cc, wrb, bg, out);
    } else {
        dim3 g(CC / BM, HWSZ / BN, BB);
        k_gemm_fb<<<g, 256, 0, stream>>>(Wbf, cc, wrb, bg, out);
    }
}